// Round 16
// baseline (19882.515 us; speedup 1.0000x reference)
//
#include <hip/hip_runtime.h>

#define B_   256
#define T_   512
#define H_   512
#define C_   10
#define NGRP 8      // batch groups (32 batches each)
#define BPG  32
#define JT   8      // j-outputs per block (halved -> 2 blocks/CU)
#define NJT  64     // blocks per batch group (512/JT)
#define KPAD 516    // LDS row stride (floats): 2064 B rows, 16B aligned
#define NTHR 128    // 2 waves/block; 2 blocks/CU -> 4 waves/CU with overlap
#define LDS_BYTES (4 * JT * KPAD * 4)   // 66048 B -> 2 blocks/CU

// numpy-SIMD-style (cephes/avx_mathfun) f32 exp — r9-flagged V2 model. DO NOT TOUCH.
__device__ __forceinline__ float expf_cephes(float x) {
    x = fminf(x, 88.3762626647949f);
    x = fmaxf(x, -88.3762626647949f);
    float fx = __fmaf_rn(x, 1.44269504088896341f, 0.5f);
    fx = floorf(fx);
    x = __fmaf_rn(fx, -0.693359375f, x);
    x = __fmaf_rn(fx, 2.12194440e-4f, x);
    float z = __fmul_rn(x, x);
    float y = 1.9875691500E-4f;
    y = __fmaf_rn(y, x, 1.3981999507E-3f);
    y = __fmaf_rn(y, x, 8.3334519073E-3f);
    y = __fmaf_rn(y, x, 4.1665795894E-2f);
    y = __fmaf_rn(y, x, 1.6666665459E-1f);
    y = __fmaf_rn(y, x, 5.0000001201E-1f);
    y = __fmaf_rn(y, z, x);
    y = __fadd_rn(y, 1.0f);
    return ldexpf(y, (int)fx);
}

__device__ __forceinline__ float sig_np(float pre) {
    float e = expf_cephes(-pre);
    return __fdiv_rn(1.0f, __fadd_rn(1.0f, e));
}

// 8 chains (2 batches x 4 gates); k-ascending — bit-identical to r12/r13/r14 order.
#define FMA8(h0, h1, w0, w1, w2, w3)                                          \
    a00 = __fmaf_rn((h0).x, (w0).x, a00); a00 = __fmaf_rn((h0).y, (w0).y, a00); \
    a00 = __fmaf_rn((h0).z, (w0).z, a00); a00 = __fmaf_rn((h0).w, (w0).w, a00); \
    a01 = __fmaf_rn((h0).x, (w1).x, a01); a01 = __fmaf_rn((h0).y, (w1).y, a01); \
    a01 = __fmaf_rn((h0).z, (w1).z, a01); a01 = __fmaf_rn((h0).w, (w1).w, a01); \
    a02 = __fmaf_rn((h0).x, (w2).x, a02); a02 = __fmaf_rn((h0).y, (w2).y, a02); \
    a02 = __fmaf_rn((h0).z, (w2).z, a02); a02 = __fmaf_rn((h0).w, (w2).w, a02); \
    a03 = __fmaf_rn((h0).x, (w3).x, a03); a03 = __fmaf_rn((h0).y, (w3).y, a03); \
    a03 = __fmaf_rn((h0).z, (w3).z, a03); a03 = __fmaf_rn((h0).w, (w3).w, a03); \
    a10 = __fmaf_rn((h1).x, (w0).x, a10); a10 = __fmaf_rn((h1).y, (w0).y, a10); \
    a10 = __fmaf_rn((h1).z, (w0).z, a10); a10 = __fmaf_rn((h1).w, (w0).w, a10); \
    a11 = __fmaf_rn((h1).x, (w1).x, a11); a11 = __fmaf_rn((h1).y, (w1).y, a11); \
    a11 = __fmaf_rn((h1).z, (w1).z, a11); a11 = __fmaf_rn((h1).w, (w1).w, a11); \
    a12 = __fmaf_rn((h1).x, (w2).x, a12); a12 = __fmaf_rn((h1).y, (w2).y, a12); \
    a12 = __fmaf_rn((h1).z, (w2).z, a12); a12 = __fmaf_rn((h1).w, (w2).w, a12); \
    a13 = __fmaf_rn((h1).x, (w3).x, a13); a13 = __fmaf_rn((h1).y, (w3).y, a13); \
    a13 = __fmaf_rn((h1).z, (w3).z, a13); a13 = __fmaf_rn((h1).w, (w3).w, a13);

__global__ void __launch_bounds__(NTHR, 1) lstm_fast(
    const float* __restrict__ x,
    const float* __restrict__ wgh, const float* __restrict__ wih,
    const float* __restrict__ wfh, const float* __restrict__ woh,
    const float* __restrict__ wgx, const float* __restrict__ wix,
    const float* __restrict__ wfx, const float* __restrict__ wox,
    const float* __restrict__ bgp, const float* __restrict__ bip,
    const float* __restrict__ bfp, const float* __restrict__ bop,
    float* __restrict__ hbuf, unsigned int* __restrict__ cnt)
{
    extern __shared__ float lds[];   // [4][JT][KPAD]
    const int tid = threadIdx.x;
    const int bg  = blockIdx.x & (NGRP - 1);
    const int jt  = blockIdx.x >> 3;          // 0..63
    const int j0  = jt * JT;

    // stage weight columns: lds[(g*JT + jj)*KPAD + k] = W[k][j0+jj]  (exact f32 bits)
    const float* wh[4] = {wgh, wih, wfh, woh};
    for (int g = 0; g < 4; ++g) {
        const float* w = wh[g];
        for (int idx = tid; idx < H_ * JT; idx += NTHR) {
            int k  = idx >> 3;            // H_*JT = 4096; k = idx / JT
            int jj = idx & (JT - 1);
            lds[(g * JT + jj) * KPAD + k] = w[k * H_ + j0 + jj];
        }
    }
    __syncthreads();

    const int jl = tid & (JT - 1);            // 0..7
    const int b2 = tid >> 3;                  // 0..15  (same role as r14's tid>>4)
    const int b0 = bg * BPG + b2 * 2;
    const int b1 = b0 + 1;
    const int jg = j0 + jl;

    const float wx0 = wgx[jg], wx1 = wix[jg], wx2 = wfx[jg], wx3 = wox[jg];
    const float bs0 = bgp[jg], bs1 = bip[jg], bs2 = bfp[jg], bs3 = bop[jg];

    const float4* wr0 = (const float4*)&lds[(0 * JT + jl) * KPAD];
    const float4* wr1 = (const float4*)&lds[(1 * JT + jl) * KPAD];
    const float4* wr2 = (const float4*)&lds[(2 * JT + jl) * KPAD];
    const float4* wr3 = (const float4*)&lds[(3 * JT + jl) * KPAD];

    float c0 = 0.f, c1 = 0.f;

    for (int t = 0; t < T_; ++t) {
        if (t > 0) {
            if (tid == 0) {
                while (__hip_atomic_load(&cnt[t * NGRP + bg], __ATOMIC_RELAXED,
                                         __HIP_MEMORY_SCOPE_AGENT) < NJT) {
                    __builtin_amdgcn_s_sleep(1);
                }
                (void)__hip_atomic_load(&cnt[t * NGRP + bg], __ATOMIC_ACQUIRE,
                                        __HIP_MEMORY_SCOPE_AGENT);
            }
            __syncthreads();
        }

        const float xt0 = x[b0 * T_ + t];
        const float xt1 = x[b1 * T_ + t];

        const float* hb = hbuf + (size_t)(t & 1) * B_ * H_;
        const float4* hr0 = (const float4*)(hb + b0 * H_);
        const float4* hr1 = (const float4*)(hb + b1 * H_);

        float a00 = 0.f, a01 = 0.f, a02 = 0.f, a03 = 0.f;
        float a10 = 0.f, a11 = 0.f, a12 = 0.f, a13 = 0.f;

        // depth-1 named-variable prefetch — byte-identical pattern to the r14 PASS
        float4 h0 = hr0[0], h1 = hr1[0];
        float4 w0 = wr0[0], w1 = wr1[0], w2 = wr2[0], w3 = wr3[0];

        #pragma unroll 4
        for (int k4 = 0; k4 < H_ / 4 - 1; ++k4) {
            float4 h0n = hr0[k4 + 1];
            float4 h1n = hr1[k4 + 1];
            float4 w0n = wr0[k4 + 1];
            float4 w1n = wr1[k4 + 1];
            float4 w2n = wr2[k4 + 1];
            float4 w3n = wr3[k4 + 1];

            FMA8(h0, h1, w0, w1, w2, w3)

            h0 = h0n; h1 = h1n;
            w0 = w0n; w1 = w1n; w2 = w2n; w3 = w3n;
        }
        FMA8(h0, h1, w0, w1, w2, w3)   // k4 = 127

        // V2 epilogue rounding, verbatim
        const float pg0 = __fadd_rn(__fadd_rn(__fmul_rn(wx0, xt0), a00), bs0);
        const float pi0 = __fadd_rn(__fadd_rn(__fmul_rn(wx1, xt0), a01), bs1);
        const float pf0 = __fadd_rn(__fadd_rn(__fmul_rn(wx2, xt0), a02), bs2);
        const float po0 = __fadd_rn(__fadd_rn(__fmul_rn(wx3, xt0), a03), bs3);
        const float i0 = sig_np(pi0), f0 = sig_np(pf0), o0 = sig_np(po0);
        c0 = __fadd_rn(__fmul_rn(pg0, i0), __fmul_rn(c0, f0));
        const float hn0 = __fmul_rn(c0, o0);

        const float pg1 = __fadd_rn(__fadd_rn(__fmul_rn(wx0, xt1), a10), bs0);
        const float pi1 = __fadd_rn(__fadd_rn(__fmul_rn(wx1, xt1), a11), bs1);
        const float pf1 = __fadd_rn(__fadd_rn(__fmul_rn(wx2, xt1), a12), bs2);
        const float po1 = __fadd_rn(__fadd_rn(__fmul_rn(wx3, xt1), a13), bs3);
        const float i1 = sig_np(pi1), f1 = sig_np(pf1), o1 = sig_np(po1);
        c1 = __fadd_rn(__fmul_rn(pg1, i1), __fmul_rn(c1, f1));
        const float hn1 = __fmul_rn(c1, o1);

        float* hw = hbuf + (size_t)((t + 1) & 1) * B_ * H_;
        hw[b0 * H_ + jg] = hn0;
        hw[b1 * H_ + jg] = hn1;

        __syncthreads();   // waves drain vmcnt before barrier -> stores complete
        if (tid == 0) {
            __threadfence();   // agent-scope release (L2 writeback) of h stores
            __hip_atomic_fetch_add(&cnt[(t + 1) * NGRP + bg], 1u,
                                   __ATOMIC_RELEASE, __HIP_MEMORY_SCOPE_AGENT);
        }
    }
}

// out[b][c] = dot_seq(h_T[b], wph[c]) + bp[c]  — bit-identical chain to r12's proj
__global__ void __launch_bounds__(64) proj_kernel(
    const float* __restrict__ hbuf, const float* __restrict__ wph,
    const float* __restrict__ bp, float* __restrict__ out)
{
    const int b = blockIdx.x, tid = threadIdx.x;
    const float* h = hbuf + (size_t)b * H_;   // final h in buffer 0 (T even)
    if (tid < C_) {
        float acc = 0.f;
        for (int k = 0; k < H_; ++k)
            acc = __fmaf_rn(h[k], wph[tid * H_ + k], acc);
        out[b * C_ + tid] = __fadd_rn(acc, bp[tid]);
    }
}

extern "C" void kernel_launch(void* const* d_in, const int* in_sizes, int n_in,
                              void* d_out, int out_size, void* d_ws, size_t ws_size,
                              hipStream_t stream)
{
    const float* x   = (const float*)d_in[0];
    const float* wgx = (const float*)d_in[1];
    const float* wgh = (const float*)d_in[2];
    const float* bgp = (const float*)d_in[3];
    const float* wix = (const float*)d_in[4];
    const float* wih = (const float*)d_in[5];
    const float* bip = (const float*)d_in[6];
    const float* wfx = (const float*)d_in[7];
    const float* wfh = (const float*)d_in[8];
    const float* bfp = (const float*)d_in[9];
    const float* wox = (const float*)d_in[10];
    const float* woh = (const float*)d_in[11];
    const float* bop = (const float*)d_in[12];
    const float* wph = (const float*)d_in[13];
    const float* bp  = (const float*)d_in[14];
    float* out = (float*)d_out;

    float* hbuf = (float*)d_ws;                                   // 2*B*H f32 = 1 MB
    unsigned int* cnt = (unsigned int*)((char*)d_ws + (size_t)2 * B_ * H_ * 4);
    size_t zero_bytes = (size_t)2 * B_ * H_ * 4 + (size_t)(T_ + 1) * NGRP * 4;
    hipMemsetAsync(d_ws, 0, zero_bytes, stream);   // h0 = 0, counters = 0

    hipFuncSetAttribute((const void*)lstm_fast,
                        hipFuncAttributeMaxDynamicSharedMemorySize, LDS_BYTES);

    void* args[] = {&x, &wgh, &wih, &wfh, &woh, &wgx, &wix, &wfx, &wox,
                    &bgp, &bip, &bfp, &bop, &hbuf, &cnt};
    hipLaunchCooperativeKernel((const void*)lstm_fast, dim3(NGRP * NJT), dim3(NTHR),
                               args, LDS_BYTES, stream);

    proj_kernel<<<B_, 64, 0, stream>>>(hbuf, wph, bp, out);
}

// Round 17
// 11900.083 us; speedup vs baseline: 1.6708x; 1.6708x over previous
//
#include <hip/hip_runtime.h>

#define B_   256
#define T_   512
#define H_   512
#define C_   10
#define NGRP 8      // batch groups (32 batches each)
#define BPG  32
#define JT   16     // j-outputs per block
#define NJT  32     // blocks per batch group
#define KPAD 516    // LDS row stride (floats): 2064 B rows, 16B aligned
#define NTHR 256
#define LDS_BYTES (4 * JT * KPAD * 4)   // 132096 B -> 1 block/CU  (r14-proven)

// numpy-SIMD-style (cephes/avx_mathfun) f32 exp — r9-flagged V2 model. DO NOT TOUCH.
__device__ __forceinline__ float expf_cephes(float x) {
    x = fminf(x, 88.3762626647949f);
    x = fmaxf(x, -88.3762626647949f);
    float fx = __fmaf_rn(x, 1.44269504088896341f, 0.5f);
    fx = floorf(fx);
    x = __fmaf_rn(fx, -0.693359375f, x);
    x = __fmaf_rn(fx, 2.12194440e-4f, x);
    float z = __fmul_rn(x, x);
    float y = 1.9875691500E-4f;
    y = __fmaf_rn(y, x, 1.3981999507E-3f);
    y = __fmaf_rn(y, x, 8.3334519073E-3f);
    y = __fmaf_rn(y, x, 4.1665795894E-2f);
    y = __fmaf_rn(y, x, 1.6666665459E-1f);
    y = __fmaf_rn(y, x, 5.0000001201E-1f);
    y = __fmaf_rn(y, z, x);
    y = __fadd_rn(y, 1.0f);
    return ldexpf(y, (int)fx);
}

__device__ __forceinline__ float sig_np(float pre) {
    float e = expf_cephes(-pre);
    return __fdiv_rn(1.0f, __fadd_rn(1.0f, e));
}

// 8 chains (2 batches x 4 gates); k-ascending — bit-identical to r12/r13/r14 order.
#define FMA8(h0, h1, w0, w1, w2, w3)                                          \
    a00 = __fmaf_rn((h0).x, (w0).x, a00); a00 = __fmaf_rn((h0).y, (w0).y, a00); \
    a00 = __fmaf_rn((h0).z, (w0).z, a00); a00 = __fmaf_rn((h0).w, (w0).w, a00); \
    a01 = __fmaf_rn((h0).x, (w1).x, a01); a01 = __fmaf_rn((h0).y, (w1).y, a01); \
    a01 = __fmaf_rn((h0).z, (w1).z, a01); a01 = __fmaf_rn((h0).w, (w1).w, a01); \
    a02 = __fmaf_rn((h0).x, (w2).x, a02); a02 = __fmaf_rn((h0).y, (w2).y, a02); \
    a02 = __fmaf_rn((h0).z, (w2).z, a02); a02 = __fmaf_rn((h0).w, (w2).w, a02); \
    a03 = __fmaf_rn((h0).x, (w3).x, a03); a03 = __fmaf_rn((h0).y, (w3).y, a03); \
    a03 = __fmaf_rn((h0).z, (w3).z, a03); a03 = __fmaf_rn((h0).w, (w3).w, a03); \
    a10 = __fmaf_rn((h1).x, (w0).x, a10); a10 = __fmaf_rn((h1).y, (w0).y, a10); \
    a10 = __fmaf_rn((h1).z, (w0).z, a10); a10 = __fmaf_rn((h1).w, (w0).w, a10); \
    a11 = __fmaf_rn((h1).x, (w1).x, a11); a11 = __fmaf_rn((h1).y, (w1).y, a11); \
    a11 = __fmaf_rn((h1).z, (w1).z, a11); a11 = __fmaf_rn((h1).w, (w1).w, a11); \
    a12 = __fmaf_rn((h1).x, (w2).x, a12); a12 = __fmaf_rn((h1).y, (w2).y, a12); \
    a12 = __fmaf_rn((h1).z, (w2).z, a12); a12 = __fmaf_rn((h1).w, (w2).w, a12); \
    a13 = __fmaf_rn((h1).x, (w3).x, a13); a13 = __fmaf_rn((h1).y, (w3).y, a13); \
    a13 = __fmaf_rn((h1).z, (w3).z, a13); a13 = __fmaf_rn((h1).w, (w3).w, a13);

// static-slot load/compute macros (NO dynamic register indexing — r15 lesson)
#define LOADS(j, n)                                                           \
    hA##j = hr0[n]; hB##j = hr1[n];                                           \
    wG##j = wr0[n]; wI##j = wr1[n]; wF##j = wr2[n]; wO##j = wr3[n];

#define STEPF(j) FMA8(hA##j, hB##j, wG##j, wI##j, wF##j, wO##j)

__global__ void __launch_bounds__(NTHR, 1) lstm_fast(
    const float* __restrict__ x,
    const float* __restrict__ wgh, const float* __restrict__ wih,
    const float* __restrict__ wfh, const float* __restrict__ woh,
    const float* __restrict__ wgx, const float* __restrict__ wix,
    const float* __restrict__ wfx, const float* __restrict__ wox,
    const float* __restrict__ bgp, const float* __restrict__ bip,
    const float* __restrict__ bfp, const float* __restrict__ bop,
    float* __restrict__ hbuf, unsigned int* __restrict__ cnt)
{
    extern __shared__ float lds[];   // [4][JT][KPAD]
    const int tid = threadIdx.x;
    const int bg  = blockIdx.x & (NGRP - 1);
    const int jt  = blockIdx.x >> 3;
    const int j0  = jt * JT;

    // stage weight columns: lds[(g*JT + jj)*KPAD + k] = W[k][j0+jj]  (exact f32 bits)
    const float* wh[4] = {wgh, wih, wfh, woh};
    for (int g = 0; g < 4; ++g) {
        const float* w = wh[g];
        for (int idx = tid; idx < H_ * JT; idx += NTHR) {
            int k  = idx >> 4;
            int jj = idx & (JT - 1);
            lds[(g * JT + jj) * KPAD + k] = w[k * H_ + j0 + jj];
        }
    }
    __syncthreads();

    const int jl = tid & (JT - 1);
    const int b2 = tid >> 4;                  // 0..15
    const int b0 = bg * BPG + b2 * 2;
    const int b1 = b0 + 1;
    const int jg = j0 + jl;

    const float wx0 = wgx[jg], wx1 = wix[jg], wx2 = wfx[jg], wx3 = wox[jg];
    const float bs0 = bgp[jg], bs1 = bip[jg], bs2 = bfp[jg], bs3 = bop[jg];

    const float4* wr0 = (const float4*)&lds[(0 * JT + jl) * KPAD];
    const float4* wr1 = (const float4*)&lds[(1 * JT + jl) * KPAD];
    const float4* wr2 = (const float4*)&lds[(2 * JT + jl) * KPAD];
    const float4* wr3 = (const float4*)&lds[(3 * JT + jl) * KPAD];

    float c0 = 0.f, c1 = 0.f;

    for (int t = 0; t < T_; ++t) {
        if (t > 0) {
            if (tid == 0) {
                while (__hip_atomic_load(&cnt[t * NGRP + bg], __ATOMIC_RELAXED,
                                         __HIP_MEMORY_SCOPE_AGENT) < NJT) {
                    __builtin_amdgcn_s_sleep(1);
                }
                (void)__hip_atomic_load(&cnt[t * NGRP + bg], __ATOMIC_ACQUIRE,
                                        __HIP_MEMORY_SCOPE_AGENT);
            }
            __syncthreads();
        }

        const float xt0 = x[b0 * T_ + t];
        const float xt1 = x[b1 * T_ + t];

        const float* hb = hbuf + (size_t)(t & 1) * B_ * H_;
        const float4* hr0 = (const float4*)(hb + b0 * H_);
        const float4* hr1 = (const float4*)(hb + b1 * H_);

        float a00 = 0.f, a01 = 0.f, a02 = 0.f, a03 = 0.f;
        float a10 = 0.f, a11 = 0.f, a12 = 0.f, a13 = 0.f;

        // 4-slot STATIC software pipeline: slot j holds iteration n,
        // refilled with n+4 right after consumption -> every load issued
        // ~3 slots (~200+ cyc of FMA issue) before use. Iterations are
        // consumed strictly ascending -> bit-identical chains to r12/r14.
        float4 hA0, hB0, wG0, wI0, wF0, wO0;
        float4 hA1, hB1, wG1, wI1, wF1, wO1;
        float4 hA2, hB2, wG2, wI2, wF2, wO2;
        float4 hA3, hB3, wG3, wI3, wF3, wO3;

        LOADS(0, 0) LOADS(1, 1) LOADS(2, 2) LOADS(3, 3)

        #pragma unroll 1
        for (int m = 0; m < 31; ++m) {
            const int n = 4 * m;
            STEPF(0) LOADS(0, n + 4)
            STEPF(1) LOADS(1, n + 5)
            STEPF(2) LOADS(2, n + 6)
            STEPF(3) LOADS(3, n + 7)
        }
        STEPF(0) STEPF(1) STEPF(2) STEPF(3)   // iterations 124..127

        // V2 epilogue rounding, verbatim
        const float pg0 = __fadd_rn(__fadd_rn(__fmul_rn(wx0, xt0), a00), bs0);
        const float pi0 = __fadd_rn(__fadd_rn(__fmul_rn(wx1, xt0), a01), bs1);
        const float pf0 = __fadd_rn(__fadd_rn(__fmul_rn(wx2, xt0), a02), bs2);
        const float po0 = __fadd_rn(__fadd_rn(__fmul_rn(wx3, xt0), a03), bs3);
        const float i0 = sig_np(pi0), f0 = sig_np(pf0), o0 = sig_np(po0);
        c0 = __fadd_rn(__fmul_rn(pg0, i0), __fmul_rn(c0, f0));
        const float hn0 = __fmul_rn(c0, o0);

        const float pg1 = __fadd_rn(__fadd_rn(__fmul_rn(wx0, xt1), a10), bs0);
        const float pi1 = __fadd_rn(__fadd_rn(__fmul_rn(wx1, xt1), a11), bs1);
        const float pf1 = __fadd_rn(__fadd_rn(__fmul_rn(wx2, xt1), a12), bs2);
        const float po1 = __fadd_rn(__fadd_rn(__fmul_rn(wx3, xt1), a13), bs3);
        const float i1 = sig_np(pi1), f1 = sig_np(pf1), o1 = sig_np(po1);
        c1 = __fadd_rn(__fmul_rn(pg1, i1), __fmul_rn(c1, f1));
        const float hn1 = __fmul_rn(c1, o1);

        float* hw = hbuf + (size_t)((t + 1) & 1) * B_ * H_;
        hw[b0 * H_ + jg] = hn0;
        hw[b1 * H_ + jg] = hn1;

        __syncthreads();   // waves drain vmcnt before barrier -> stores complete
        if (tid == 0) {
            __threadfence();   // agent-scope release (L2 writeback) of h stores
            __hip_atomic_fetch_add(&cnt[(t + 1) * NGRP + bg], 1u,
                                   __ATOMIC_RELEASE, __HIP_MEMORY_SCOPE_AGENT);
        }
    }
}

// out[b][c] = dot_seq(h_T[b], wph[c]) + bp[c]  — bit-identical chain to r12's proj
__global__ void __launch_bounds__(64) proj_kernel(
    const float* __restrict__ hbuf, const float* __restrict__ wph,
    const float* __restrict__ bp, float* __restrict__ out)
{
    const int b = blockIdx.x, tid = threadIdx.x;
    const float* h = hbuf + (size_t)b * H_;   // final h in buffer 0 (T even)
    if (tid < C_) {
        float acc = 0.f;
        for (int k = 0; k < H_; ++k)
            acc = __fmaf_rn(h[k], wph[tid * H_ + k], acc);
        out[b * C_ + tid] = __fadd_rn(acc, bp[tid]);
    }
}

extern "C" void kernel_launch(void* const* d_in, const int* in_sizes, int n_in,
                              void* d_out, int out_size, void* d_ws, size_t ws_size,
                              hipStream_t stream)
{
    const float* x   = (const float*)d_in[0];
    const float* wgx = (const float*)d_in[1];
    const float* wgh = (const float*)d_in[2];
    const float* bgp = (const float*)d_in[3];
    const float* wix = (const float*)d_in[4];
    const float* wih = (const float*)d_in[5];
    const float* bip = (const float*)d_in[6];
    const float* wfx = (const float*)d_in[7];
    const float* wfh = (const float*)d_in[8];
    const float* bfp = (const float*)d_in[9];
    const float* wox = (const float*)d_in[10];
    const float* woh = (const float*)d_in[11];
    const float* bop = (const float*)d_in[12];
    const float* wph = (const float*)d_in[13];
    const float* bp  = (const float*)d_in[14];
    float* out = (float*)d_out;

    float* hbuf = (float*)d_ws;                                   // 2*B*H f32 = 1 MB
    unsigned int* cnt = (unsigned int*)((char*)d_ws + (size_t)2 * B_ * H_ * 4);
    size_t zero_bytes = (size_t)2 * B_ * H_ * 4 + (size_t)(T_ + 1) * NGRP * 4;
    hipMemsetAsync(d_ws, 0, zero_bytes, stream);   // h0 = 0, counters = 0

    hipFuncSetAttribute((const void*)lstm_fast,
                        hipFuncAttributeMaxDynamicSharedMemorySize, LDS_BYTES);

    void* args[] = {&x, &wgh, &wih, &wfh, &woh, &wgx, &wix, &wfx, &wox,
                    &bgp, &bip, &bfp, &bop, &hbuf, &cnt};
    hipLaunchCooperativeKernel((const void*)lstm_fast, dim3(NGRP * NJT), dim3(NTHR),
                               args, LDS_BYTES, stream);

    proj_kernel<<<B_, 64, 0, stream>>>(hbuf, wph, bp, out);
}

// Round 18
// 9728.297 us; speedup vs baseline: 2.0438x; 1.2232x over previous
//
#include <hip/hip_runtime.h>

#define B_   256
#define T_   512
#define H_   512
#define C_   10
#define NGRP 8      // batch groups (32 batches each)
#define BPG  32
#define JT   16     // j-outputs per block
#define NJT  32     // blocks per batch group
#define KPAD 516    // LDS row stride (floats): 2064 B rows, 16B aligned
#define NTHR 256
#define LDS_BYTES (4 * JT * KPAD * 4)   // 132096 B -> 1 block/CU  (r14/r17-proven)

// numpy-SIMD-style (cephes/avx_mathfun) f32 exp — r9-flagged V2 model. DO NOT TOUCH.
__device__ __forceinline__ float expf_cephes(float x) {
    x = fminf(x, 88.3762626647949f);
    x = fmaxf(x, -88.3762626647949f);
    float fx = __fmaf_rn(x, 1.44269504088896341f, 0.5f);
    fx = floorf(fx);
    x = __fmaf_rn(fx, -0.693359375f, x);
    x = __fmaf_rn(fx, 2.12194440e-4f, x);
    float z = __fmul_rn(x, x);
    float y = 1.9875691500E-4f;
    y = __fmaf_rn(y, x, 1.3981999507E-3f);
    y = __fmaf_rn(y, x, 8.3334519073E-3f);
    y = __fmaf_rn(y, x, 4.1665795894E-2f);
    y = __fmaf_rn(y, x, 1.6666665459E-1f);
    y = __fmaf_rn(y, x, 5.0000001201E-1f);
    y = __fmaf_rn(y, z, x);
    y = __fadd_rn(y, 1.0f);
    return ldexpf(y, (int)fx);
}

__device__ __forceinline__ float sig_np(float pre) {
    float e = expf_cephes(-pre);
    return __fdiv_rn(1.0f, __fadd_rn(1.0f, e));
}

// 8 chains (2 batches x 4 gates); k-ascending — bit-identical to r12/r14/r17 order.
#define FMA8(h0, h1, w0, w1, w2, w3)                                          \
    a00 = __fmaf_rn((h0).x, (w0).x, a00); a00 = __fmaf_rn((h0).y, (w0).y, a00); \
    a00 = __fmaf_rn((h0).z, (w0).z, a00); a00 = __fmaf_rn((h0).w, (w0).w, a00); \
    a01 = __fmaf_rn((h0).x, (w1).x, a01); a01 = __fmaf_rn((h0).y, (w1).y, a01); \
    a01 = __fmaf_rn((h0).z, (w1).z, a01); a01 = __fmaf_rn((h0).w, (w1).w, a01); \
    a02 = __fmaf_rn((h0).x, (w2).x, a02); a02 = __fmaf_rn((h0).y, (w2).y, a02); \
    a02 = __fmaf_rn((h0).z, (w2).z, a02); a02 = __fmaf_rn((h0).w, (w2).w, a02); \
    a03 = __fmaf_rn((h0).x, (w3).x, a03); a03 = __fmaf_rn((h0).y, (w3).y, a03); \
    a03 = __fmaf_rn((h0).z, (w3).z, a03); a03 = __fmaf_rn((h0).w, (w3).w, a03); \
    a10 = __fmaf_rn((h1).x, (w0).x, a10); a10 = __fmaf_rn((h1).y, (w0).y, a10); \
    a10 = __fmaf_rn((h1).z, (w0).z, a10); a10 = __fmaf_rn((h1).w, (w0).w, a10); \
    a11 = __fmaf_rn((h1).x, (w1).x, a11); a11 = __fmaf_rn((h1).y, (w1).y, a11); \
    a11 = __fmaf_rn((h1).z, (w1).z, a11); a11 = __fmaf_rn((h1).w, (w1).w, a11); \
    a12 = __fmaf_rn((h1).x, (w2).x, a12); a12 = __fmaf_rn((h1).y, (w2).y, a12); \
    a12 = __fmaf_rn((h1).z, (w2).z, a12); a12 = __fmaf_rn((h1).w, (w2).w, a12); \
    a13 = __fmaf_rn((h1).x, (w3).x, a13); a13 = __fmaf_rn((h1).y, (w3).y, a13); \
    a13 = __fmaf_rn((h1).z, (w3).z, a13); a13 = __fmaf_rn((h1).w, (w3).w, a13);

// static-slot load/compute macros (NO dynamic register indexing — r15 lesson)
#define LOADS(j, n)                                                           \
    hA##j = hr0[n]; hB##j = hr1[n];                                           \
    wG##j = wr0[n]; wI##j = wr1[n]; wF##j = wr2[n]; wO##j = wr3[n];

#define STEPF(j) FMA8(hA##j, hB##j, wG##j, wI##j, wF##j, wO##j)

__global__ void __launch_bounds__(NTHR, 1) lstm_fast(
    const float* __restrict__ x,
    const float* __restrict__ wgh, const float* __restrict__ wih,
    const float* __restrict__ wfh, const float* __restrict__ woh,
    const float* __restrict__ wgx, const float* __restrict__ wix,
    const float* __restrict__ wfx, const float* __restrict__ wox,
    const float* __restrict__ bgp, const float* __restrict__ bip,
    const float* __restrict__ bfp, const float* __restrict__ bop,
    float* __restrict__ hbuf, unsigned int* __restrict__ cnt)
{
    extern __shared__ float lds[];   // [4][JT][KPAD]
    const int tid = threadIdx.x;
    const int bg  = blockIdx.x & (NGRP - 1);
    const int jt  = blockIdx.x >> 3;
    const int j0  = jt * JT;

    // stage weight columns: lds[(g*JT + jj)*KPAD + k] = W[k][j0+jj]  (exact f32 bits)
    const float* wh[4] = {wgh, wih, wfh, woh};
    for (int g = 0; g < 4; ++g) {
        const float* w = wh[g];
        for (int idx = tid; idx < H_ * JT; idx += NTHR) {
            int k  = idx >> 4;
            int jj = idx & (JT - 1);
            lds[(g * JT + jj) * KPAD + k] = w[k * H_ + j0 + jj];
        }
    }
    __syncthreads();

    const int jl = tid & (JT - 1);
    const int b2 = tid >> 4;                  // 0..15
    const int b0 = bg * BPG + b2 * 2;
    const int b1 = b0 + 1;
    const int jg = j0 + jl;

    const float wx0 = wgx[jg], wx1 = wix[jg], wx2 = wfx[jg], wx3 = wox[jg];
    const float bs0 = bgp[jg], bs1 = bip[jg], bs2 = bfp[jg], bs3 = bop[jg];

    const float4* wr0 = (const float4*)&lds[(0 * JT + jl) * KPAD];
    const float4* wr1 = (const float4*)&lds[(1 * JT + jl) * KPAD];
    const float4* wr2 = (const float4*)&lds[(2 * JT + jl) * KPAD];
    const float4* wr3 = (const float4*)&lds[(3 * JT + jl) * KPAD];

    float c0 = 0.f, c1 = 0.f;

    for (int t = 0; t < T_; ++t) {
        if (t > 0) {
            if (tid == 0) {
                while (__hip_atomic_load(&cnt[t * NGRP + bg], __ATOMIC_RELAXED,
                                         __HIP_MEMORY_SCOPE_AGENT) < NJT) {
                    __builtin_amdgcn_s_sleep(1);
                }
                (void)__hip_atomic_load(&cnt[t * NGRP + bg], __ATOMIC_ACQUIRE,
                                        __HIP_MEMORY_SCOPE_AGENT);
            }
            __syncthreads();
        }

        const float xt0 = x[b0 * T_ + t];
        const float xt1 = x[b1 * T_ + t];

        const float* hb = hbuf + (size_t)(t & 1) * B_ * H_;
        const float4* hr0 = (const float4*)(hb + b0 * H_);
        const float4* hr1 = (const float4*)(hb + b1 * H_);

        float a00 = 0.f, a01 = 0.f, a02 = 0.f, a03 = 0.f;
        float a10 = 0.f, a11 = 0.f, a12 = 0.f, a13 = 0.f;

        // 4-slot STATIC software pipeline (r17-proven): slot j consumed then
        // refilled with iteration n+4 -> loads issued ~200+ cyc before use.
        // Iterations consumed strictly ascending -> bit-identical chains.
        float4 hA0, hB0, wG0, wI0, wF0, wO0;
        float4 hA1, hB1, wG1, wI1, wF1, wO1;
        float4 hA2, hB2, wG2, wI2, wF2, wO2;
        float4 hA3, hB3, wG3, wI3, wF3, wO3;

        LOADS(0, 0) LOADS(1, 1) LOADS(2, 2) LOADS(3, 3)

        #pragma unroll 1
        for (int m = 0; m < 31; ++m) {
            const int n = 4 * m;
            STEPF(0) LOADS(0, n + 4)
            STEPF(1) LOADS(1, n + 5)
            STEPF(2) LOADS(2, n + 6)
            STEPF(3) LOADS(3, n + 7)
        }
        STEPF(0) STEPF(1) STEPF(2) STEPF(3)   // iterations 124..127

        // V2 epilogue rounding, verbatim
        const float pg0 = __fadd_rn(__fadd_rn(__fmul_rn(wx0, xt0), a00), bs0);
        const float pi0 = __fadd_rn(__fadd_rn(__fmul_rn(wx1, xt0), a01), bs1);
        const float pf0 = __fadd_rn(__fadd_rn(__fmul_rn(wx2, xt0), a02), bs2);
        const float po0 = __fadd_rn(__fadd_rn(__fmul_rn(wx3, xt0), a03), bs3);
        const float i0 = sig_np(pi0), f0 = sig_np(pf0), o0 = sig_np(po0);
        c0 = __fadd_rn(__fmul_rn(pg0, i0), __fmul_rn(c0, f0));
        const float hn0 = __fmul_rn(c0, o0);

        const float pg1 = __fadd_rn(__fadd_rn(__fmul_rn(wx0, xt1), a10), bs0);
        const float pi1 = __fadd_rn(__fadd_rn(__fmul_rn(wx1, xt1), a11), bs1);
        const float pf1 = __fadd_rn(__fadd_rn(__fmul_rn(wx2, xt1), a12), bs2);
        const float po1 = __fadd_rn(__fadd_rn(__fmul_rn(wx3, xt1), a13), bs3);
        const float i1 = sig_np(pi1), f1 = sig_np(pf1), o1 = sig_np(po1);
        c1 = __fadd_rn(__fmul_rn(pg1, i1), __fmul_rn(c1, f1));
        const float hn1 = __fmul_rn(c1, o1);

        float* hw = hbuf + (size_t)((t + 1) & 1) * B_ * H_;
        hw[b0 * H_ + jg] = hn0;
        hw[b1 * H_ + jg] = hn1;

        __syncthreads();   // s_waitcnt vmcnt(0) before s_barrier: h stores drained
        if (tid == 0) {
            // RELEASE fetch_add alone provides the store->flag release fence
            // (wbl2). The previous explicit __threadfence() duplicated it —
            // removed (one redundant full-L2 writeback per step per block).
            __hip_atomic_fetch_add(&cnt[(t + 1) * NGRP + bg], 1u,
                                   __ATOMIC_RELEASE, __HIP_MEMORY_SCOPE_AGENT);
        }
    }
}

// out[b][c] = dot_seq(h_T[b], wph[c]) + bp[c]  — bit-identical chain to r12's proj
__global__ void __launch_bounds__(64) proj_kernel(
    const float* __restrict__ hbuf, const float* __restrict__ wph,
    const float* __restrict__ bp, float* __restrict__ out)
{
    const int b = blockIdx.x, tid = threadIdx.x;
    const float* h = hbuf + (size_t)b * H_;   // final h in buffer 0 (T even)
    if (tid < C_) {
        float acc = 0.f;
        for (int k = 0; k < H_; ++k)
            acc = __fmaf_rn(h[k], wph[tid * H_ + k], acc);
        out[b * C_ + tid] = __fadd_rn(acc, bp[tid]);
    }
}

extern "C" void kernel_launch(void* const* d_in, const int* in_sizes, int n_in,
                              void* d_out, int out_size, void* d_ws, size_t ws_size,
                              hipStream_t stream)
{
    const float* x   = (const float*)d_in[0];
    const float* wgx = (const float*)d_in[1];
    const float* wgh = (const float*)d_in[2];
    const float* bgp = (const float*)d_in[3];
    const float* wix = (const float*)d_in[4];
    const float* wih = (const float*)d_in[5];
    const float* bip = (const float*)d_in[6];
    const float* wfx = (const float*)d_in[7];
    const float* wfh = (const float*)d_in[8];
    const float* bfp = (const float*)d_in[9];
    const float* wox = (const float*)d_in[10];
    const float* woh = (const float*)d_in[11];
    const float* bop = (const float*)d_in[12];
    const float* wph = (const float*)d_in[13];
    const float* bp  = (const float*)d_in[14];
    float* out = (float*)d_out;

    float* hbuf = (float*)d_ws;                                   // 2*B*H f32 = 1 MB
    unsigned int* cnt = (unsigned int*)((char*)d_ws + (size_t)2 * B_ * H_ * 4);
    size_t zero_bytes = (size_t)2 * B_ * H_ * 4 + (size_t)(T_ + 1) * NGRP * 4;
    hipMemsetAsync(d_ws, 0, zero_bytes, stream);   // h0 = 0, counters = 0

    hipFuncSetAttribute((const void*)lstm_fast,
                        hipFuncAttributeMaxDynamicSharedMemorySize, LDS_BYTES);

    void* args[] = {&x, &wgh, &wih, &wfh, &woh, &wgx, &wix, &wfx, &wox,
                    &bgp, &bip, &bfp, &bop, &hbuf, &cnt};
    hipLaunchCooperativeKernel((const void*)lstm_fast, dim3(NGRP * NJT), dim3(NTHR),
                               args, LDS_BYTES, stream);

    proj_kernel<<<B_, 64, 0, stream>>>(hbuf, wph, bp, out);
}